// Round 11
// baseline (364.131 us; speedup 1.0000x reference)
//
#include <hip/hip_runtime.h>
#include <math.h>

// ---------------------------------------------------------------------------
// LinSinkhornPRModel: sigmoid(dist2 - dist1) of two Sinkhorn divergences.
//   - f_aa self-term cancels in dist2-dist1 -> C_xx never built.
//   - R10: 364us. k_round5 counters: VGPR 76 (occupancy cliff at 64 -> 4
//     waves/SIMD), grid 768 = 12 waves/CU, 196K LDS bank conflicts -> ~75%
//     stall vs 5us issue floor.
//   - R11: 8-row streaming tiles (1536 blocks, 6/CU), online col accums
//     (~55 VGPR, launch_bounds(256,8)), conflict-free 32-thr/row reduce,
//     float2-packed partials (nchunk 512).
// ---------------------------------------------------------------------------

typedef __attribute__((ext_vector_type(8))) short short8;
typedef __attribute__((ext_vector_type(4))) float f32x4;
typedef __attribute__((ext_vector_type(8))) unsigned short u16x8;
typedef __attribute__((ext_vector_type(4))) unsigned short u16x4;

#define LOG2E 1.4426950408889634
#define LN2   0.6931471805599453

__device__ __forceinline__ float exp2fast(float x){
#if __has_builtin(__builtin_amdgcn_exp2f)
    return __builtin_amdgcn_exp2f(x);
#else
    return exp2f(x);
#endif
}
__device__ __forceinline__ void lse2_upd(float& m, float& s, float v){
    float M2 = fmaxf(m, v);
    s = s * exp2fast(m - M2) + exp2fast(v - M2);
    m = M2;
}
__device__ __forceinline__ void lse2_merge(float& m, float& s, float mo, float so){
    float M2 = fmaxf(m, mo);
    s = s * exp2fast(m - M2) + so * exp2fast(mo - M2);
    m = M2;
}
__device__ __forceinline__ unsigned short f2bf(float x){
    unsigned u = __float_as_uint(x);
    unsigned r = u + 0x7fffu + ((u >> 16) & 1u);
    return (unsigned short)(r >> 16);
}
__device__ __forceinline__ float h2f(unsigned short u){
    _Float16 h; __builtin_memcpy(&h, &u, 2); return (float)h;
}
__device__ __forceinline__ unsigned short f2h(float f){
    _Float16 h = (_Float16)f; unsigned short u; __builtin_memcpy(&u, &h, 2); return u;
}
__device__ __forceinline__ float max8(const float* v){
    return fmaxf(fmaxf(fmaxf(v[0], v[1]), fmaxf(v[2], v[3])),
                 fmaxf(fmaxf(v[4], v[5]), fmaxf(v[6], v[7])));
}

// ----------------------------- setup kernels -------------------------------

__global__ void k_transposeW(const float* __restrict__ W, float* __restrict__ WT){
    int b = blockIdx.x, t = threadIdx.x;   // WT[k][o] = W[o][k]
    WT[b * 128 + t] = W[t * 128 + b];
}

__global__ __launch_bounds__(128)
void k_transform_all(const float* __restrict__ d, const float* __restrict__ si,
                     const float* __restrict__ sj, const float* __restrict__ WT,
                     unsigned short* __restrict__ th, float* __restrict__ hn)
{
    __shared__ float xs[8][128];
    __shared__ float red[16];
    const int t = threadIdx.x;
    const int r0 = blockIdx.x * 8;
    const float* src; int sr;
    if (r0 < 4096)      { src = d;  sr = r0; }
    else if (r0 < 6144) { src = si; sr = r0 - 4096; }
    else                { src = sj; sr = r0 - 6144; }
    for (int rr = 0; rr < 8; ++rr)
        xs[rr][t] = src[(size_t)(sr + rr) * 128 + t];
    __syncthreads();
    float acc[8];
#pragma unroll
    for (int rr = 0; rr < 8; ++rr) acc[rr] = 0.f;
    for (int k = 0; k < 128; ++k) {
        float wv = WT[k * 128 + t];
#pragma unroll
        for (int rr = 0; rr < 8; ++rr) acc[rr] = fmaf(xs[rr][k], wv, acc[rr]);
    }
#pragma unroll
    for (int rr = 0; rr < 8; ++rr) {
        float a = acc[rr];
        th[(size_t)(r0 + rr) * 128 + t] = f2bf(a);
        float sq = a * a;
#pragma unroll
        for (int o = 1; o < 64; o <<= 1) sq += __shfl_xor(sq, o);
        if ((t & 63) == 0) red[(t >> 6) * 8 + rr] = sq;
    }
    __syncthreads();
    if (t < 8) hn[r0 + t] = 0.5f * (red[t] + red[8 + t]);
}

__global__ void k_log_all(const float* __restrict__ h, const float* __restrict__ hi,
                          const float* __restrict__ hj, float* __restrict__ lg)
{
    int i = blockIdx.x * 256 + threadIdx.x;   // 8192 total
    float x;
    if (i < 4096)      x = h[i];
    else if (i < 6144) x = hi[i - 4096];
    else               x = hj[i - 6144];
    lg[i] = __log2f(x);
}

// ------------------------------ cost GEMM (MFMA) ---------------------------
// C[i][j] = max(hna[i]+hnb[j]-dot, 0) fp16; single bf16 pass.
struct CostPair {
    const unsigned short *Ah, *Bh;
    const float *hna, *hnb;
    unsigned short* C; int ldc;
};

#define CPAD 140

__global__ __launch_bounds__(256)
void k_cost_mfma(CostPair P)
{
    const int i0 = blockIdx.y * 64, j0 = blockIdx.x * 128;
    const int w = threadIdx.x >> 6, lane = threadIdx.x & 63;
    const int rh = w >> 1, ch = w & 1;
    const int ar = i0 + rh * 32;
    const int bc = j0 + ch * 64;
    const int lrow = lane & 15;
    const int kgrp = (lane >> 4) * 8;

    __shared__ unsigned short lds_c[64][CPAD];

    f32x4 acc[2][4];
#pragma unroll
    for (int a = 0; a < 2; ++a)
#pragma unroll
        for (int c = 0; c < 4; ++c) acc[a][c] = (f32x4){0.f, 0.f, 0.f, 0.f};

    short8 ah[2][4], bh[4][4];
#pragma unroll
    for (int kc = 0; kc < 4; ++kc) {
#pragma unroll
        for (int f = 0; f < 2; ++f)
            ah[f][kc] = *reinterpret_cast<const short8*>(
                P.Ah + (size_t)(ar + f * 16 + lrow) * 128 + kc * 32 + kgrp);
#pragma unroll
        for (int f = 0; f < 4; ++f)
            bh[f][kc] = *reinterpret_cast<const short8*>(
                P.Bh + (size_t)(bc + f * 16 + lrow) * 128 + kc * 32 + kgrp);
    }
#pragma unroll
    for (int kc = 0; kc < 4; ++kc)
#pragma unroll
        for (int fi = 0; fi < 2; ++fi)
#pragma unroll
            for (int fj = 0; fj < 4; ++fj)
                acc[fi][fj] = __builtin_amdgcn_mfma_f32_16x16x32_bf16(
                    bh[fj][kc], ah[fi][kc], acc[fi][fj], 0, 0, 0);

    // C^T frag -> LDS stage
    const int rloc = lane & 15, cloc = (lane >> 4) * 4;
#pragma unroll
    for (int fi = 0; fi < 2; ++fi) {
        int lr = rh * 32 + fi * 16 + rloc;
        float ha = P.hna[i0 + lr];
#pragma unroll
        for (int fj = 0; fj < 4; ++fj) {
            int lc = ch * 64 + fj * 16 + cloc;
            f32x4 hb = *reinterpret_cast<const f32x4*>(P.hnb + j0 + lc);
            u16x4 v;
#pragma unroll
            for (int e = 0; e < 4; ++e)
                v[e] = f2h(fmaxf(ha + hb[e] - acc[fi][fj][e], 0.f));
            *reinterpret_cast<u16x4*>(&lds_c[lr][lc]) = v;
        }
    }
    __syncthreads();
    {
        const int row = threadIdx.x >> 2, q = threadIdx.x & 3;
        const unsigned short* srcp = &lds_c[row][q * 32];
        unsigned short* dstp = P.C + (size_t)(i0 + row) * P.ldc + j0 + q * 32;
#pragma unroll
        for (int k = 0; k < 4; ++k)
            *reinterpret_cast<u16x8*>(dstp + 8 * k) =
                *reinterpret_cast<const u16x8*>(srcp + 8 * k);
    }
}

// ------------------------------ round kernel -------------------------------
// 8 rows x 2048 cols streaming; thread t owns cols [8t,8t+8).
// Per row: load u16x8, row two-pass LSE (1 exp2/elem) -> LDS; col online
// lse2_upd (2 exp2/elem, 8 independent chains). Reduce: 32 thr/row, stride
// 256 (2-way bank alias only = free), 7 serial merges + 5-level shfl.
// Partials packed float2 {m,s} -> [512][2048].

struct R5Task {
    const unsigned short* C;
    const float* WB; const float* WA;
    const float* fold; const float* la;
    float* fout; float* fwout;
    float* pms;                         // float2-packed [512][2048]
    int blk0;
};
struct R5YTask {
    const unsigned short* C; const float* Wv;
    const float* fold; const float* logself;
    float* vout; float* wout;
    int blk0;
};
struct R5Args {
    R5Task d[2]; R5YTask y[2];
    float ie2, epsln2, ie2n, alpha, beta;
    int yblk0;
};

__global__ __launch_bounds__(256, 8)
void k_round6(R5Args A)
{
    __shared__ float lmS[8][256];
    __shared__ float lsS[8][256];
    const int b = blockIdx.x;
    const int tid = threadIdx.x;
    const float nie2 = -A.ie2;
    const int c0 = tid * 8;

    if (b >= A.yblk0) {
        // ---- yy row-only tile ----
        R5YTask T = (b >= A.y[1].blk0) ? A.y[1] : A.y[0];
        const int chunk = b - T.blk0;
        const int row0 = chunk * 8;
        float wb[8];
#pragma unroll
        for (int e = 0; e < 8; ++e) wb[e] = T.Wv[c0 + e];
#pragma unroll
        for (int r = 0; r < 8; ++r) {
            u16x8 c = *reinterpret_cast<const u16x8*>(T.C + (size_t)(row0 + r) * 2048 + c0);
            float v[8];
#pragma unroll
            for (int e = 0; e < 8; ++e) v[e] = fmaf(h2f(c[e]), nie2, wb[e]);
            float M8 = max8(v);
            float s8 = 0.f;
#pragma unroll
            for (int e = 0; e < 8; ++e) s8 += exp2fast(v[e] - M8);
            lmS[r][tid] = M8; lsS[r][tid] = s8;
        }
        __syncthreads();
        {
            const int row = tid >> 5, g = tid & 31;
            float m = lmS[row][g], s = lsS[row][g];
#pragma unroll
            for (int k = 1; k < 8; ++k)
                lse2_merge(m, s, lmS[row][g + 32 * k], lsS[row][g + 32 * k]);
#pragma unroll
            for (int o = 1; o < 32; o <<= 1) {
                float mo = __shfl_xor(m, o), so = __shfl_xor(s, o);
                lse2_merge(m, s, mo, so);
            }
            if (g == 0) {
                int rr = row0 + row;
                float val  = -A.epsln2 * (m + __log2f(s));
                float vnew = A.alpha * T.fold[rr] + A.beta * val;
                T.vout[rr] = vnew;
                T.wout[rr] = fmaf(vnew, A.ie2n, T.logself[rr]);
            }
        }
        return;
    }

    // ---- dual xy tile ----
    R5Task T = (b >= A.d[1].blk0) ? A.d[1] : A.d[0];
    const int chunk = b - T.blk0;
    const int row0 = chunk * 8;
    float wb[8];
#pragma unroll
    for (int e = 0; e < 8; ++e) wb[e] = T.WB[c0 + e];
    float mcol[8], scol[8];
#pragma unroll
    for (int e = 0; e < 8; ++e) { mcol[e] = -INFINITY; scol[e] = 0.f; }

#pragma unroll
    for (int r = 0; r < 8; ++r) {
        u16x8 c = *reinterpret_cast<const u16x8*>(T.C + (size_t)(row0 + r) * 2048 + c0);
        const float wa = T.WA[row0 + r];
        float u[8], v[8];
#pragma unroll
        for (int e = 0; e < 8; ++e) { u[e] = h2f(c[e]) * nie2; v[e] = u[e] + wb[e]; }
        float M8 = max8(v);
        float s8 = 0.f;
#pragma unroll
        for (int e = 0; e < 8; ++e) s8 += exp2fast(v[e] - M8);
        lmS[r][tid] = M8; lsS[r][tid] = s8;
#pragma unroll
        for (int e = 0; e < 8; ++e) lse2_upd(mcol[e], scol[e], u[e] + wa);
    }
    // packed float2 partial store (64B contiguous per thread)
    {
        float* pp = T.pms + ((size_t)chunk * 2048 + c0) * 2;
        f32x4 q0 = { mcol[0], scol[0], mcol[1], scol[1] };
        f32x4 q1 = { mcol[2], scol[2], mcol[3], scol[3] };
        f32x4 q2 = { mcol[4], scol[4], mcol[5], scol[5] };
        f32x4 q3 = { mcol[6], scol[6], mcol[7], scol[7] };
        *reinterpret_cast<f32x4*>(pp)      = q0;
        *reinterpret_cast<f32x4*>(pp + 4)  = q1;
        *reinterpret_cast<f32x4*>(pp + 8)  = q2;
        *reinterpret_cast<f32x4*>(pp + 12) = q3;
    }
    __syncthreads();
    {
        const int row = tid >> 5, g = tid & 31;
        float m = lmS[row][g], s = lsS[row][g];
#pragma unroll
        for (int k = 1; k < 8; ++k)
            lse2_merge(m, s, lmS[row][g + 32 * k], lsS[row][g + 32 * k]);
#pragma unroll
        for (int o = 1; o < 32; o <<= 1) {
            float mo = __shfl_xor(m, o), so = __shfl_xor(s, o);
            lse2_merge(m, s, mo, so);
        }
        if (g == 0) {
            int rr = row0 + row;
            float val  = -A.epsln2 * (m + __log2f(s));
            float vnew = A.alpha * T.fold[rr] + A.beta * val;
            T.fout[rr] = vnew;
            T.fwout[rr] = fmaf(vnew, A.ie2n, T.la[rr]);
        }
    }
}

// ------------------------------ combine kernel -----------------------------
// 512 blocks; 8 cols x 32 chunk-groups. float2-packed partial reads (8B).
struct CombA { const float* pms; const float* gold; const float* lb;
               float* gout; float* gwout; };
struct C4Args { CombA a[2]; float epsln2, ie2n, alpha, beta; };

__global__ __launch_bounds__(256)
void k_comb5(C4Args A)
{
    const int b = blockIdx.x;             // 512 blocks: 256 per task
    const int tid = threadIdx.x;
    const int lane = tid & 63, w = tid >> 6;
    CombA T = A.a[b >> 8];
    const int jl = tid & 7;
    const int j = (b & 255) * 8 + jl;
    const int cg = tid >> 3;              // 0..31
    float m = -INFINITY, s = 0.f;
#pragma unroll
    for (int k = 0; k < 16; ++k) {
        int c = cg + 32 * k;
        const float* p = T.pms + ((size_t)c * 2048 + j) * 2;
        lse2_merge(m, s, p[0], p[1]);
    }
#pragma unroll
    for (int o = 8; o <= 32; o <<= 1) {
        float mo = __shfl_xor(m, o), so = __shfl_xor(s, o);
        lse2_merge(m, s, mo, so);
    }
    __shared__ float smm[4][8], sss[4][8];
    if (lane < 8) { smm[w][lane] = m; sss[w][lane] = s; }
    __syncthreads();
    if (tid < 8) {
        m = smm[0][tid]; s = sss[0][tid];
#pragma unroll
        for (int q = 1; q < 4; ++q) lse2_merge(m, s, smm[q][tid], sss[q][tid]);
        int jj = (b & 255) * 8 + tid;
        float val = -A.epsln2 * (m + __log2f(s));
        float gnew = A.alpha * T.gold[jj] + A.beta * val;
        T.gout[jj] = gnew;
        T.gwout[jj] = fmaf(gnew, A.ie2n, T.lb[jj]);
    }
}

// ------------------------------ final reduce -------------------------------
__global__ __launch_bounds__(1024)
void k_final(const float* __restrict__ h, const float* __restrict__ hi,
             const float* __restrict__ hj,
             const float* __restrict__ f1f, const float* __restrict__ f2f,
             const float* __restrict__ g1f, const float* __restrict__ gb1f,
             const float* __restrict__ g2f, const float* __restrict__ gb2f,
             int N, int M, float* __restrict__ out)
{
    float acc = 0.f;
    for (int i = threadIdx.x; i < N; i += 1024)
        acc += h[i] * (f2f[i] - f1f[i]);
    for (int j = threadIdx.x; j < M; j += 1024)
        acc += hj[j] * (g2f[j] - gb2f[j]) - hi[j] * (g1f[j] - gb1f[j]);
#pragma unroll
    for (int o = 32; o; o >>= 1) acc += __shfl_xor(acc, o);
    __shared__ float red[16];
    const int lane = threadIdx.x & 63, w = threadIdx.x >> 6;
    if (lane == 0) red[w] = acc;
    __syncthreads();
    if (threadIdx.x == 0) {
        float t = 0.f;
        for (int q = 0; q < 16; ++q) t += red[q];
        out[0] = 1.f / (1.f + expf(-t));   // SCALING_FACTOR = 1
    }
}

// ------------------------------ orchestration ------------------------------

extern "C" void kernel_launch(void* const* d_in, const int* in_sizes, int n_in,
                              void* d_out, int out_size, void* d_ws, size_t ws_size,
                              hipStream_t stream)
{
    const float* d  = (const float*)d_in[0];
    const float* si = (const float*)d_in[1];
    const float* sj = (const float*)d_in[2];
    const float* h  = (const float*)d_in[3];
    const float* hi = (const float*)d_in[4];
    const float* hj = (const float*)d_in[5];
    const float* W  = (const float*)d_in[6];
    float* out = (float*)d_out;

    const int N = 4096, M = 2048;
    (void)in_sizes; (void)n_in; (void)out_size; (void)ws_size;

    float* ws = (float*)d_ws;
    size_t off = 0;
    auto alloc = [&](size_t n) { float* p = ws + off; off += (n + 63) & ~(size_t)63; return p; };

    float* WT    = alloc(128 * 128);
    float* lg2   = alloc(8192);
    float* hnAll = alloc(8192);
    unsigned short* thAll = (unsigned short*)alloc(8192 * 128 / 2);
    float* f1[2]  = { alloc(N), alloc(N) };
    float* f2[2]  = { alloc(N), alloc(N) };
    float* g1[2]  = { alloc(M), alloc(M) };
    float* g2[2]  = { alloc(M), alloc(M) };
    float* gb1[2] = { alloc(M), alloc(M) };
    float* gb2[2] = { alloc(M), alloc(M) };
    float* WA1[2] = { alloc(N), alloc(N) };
    float* WA2[2] = { alloc(N), alloc(N) };
    float* WB1[2] = { alloc(M), alloc(M) };
    float* WB2[2] = { alloc(M), alloc(M) };
    float* WY1[2] = { alloc(M), alloc(M) };
    float* WY2[2] = { alloc(M), alloc(M) };
    float* f1f = alloc(N); float* f2f = alloc(N);
    float* g1f = alloc(M); float* g2f = alloc(M);
    float* gb1f = alloc(M); float* gb2f = alloc(M);
    unsigned short* C1  = (unsigned short*)alloc((size_t)N * M / 2);
    unsigned short* C2  = (unsigned short*)alloc((size_t)N * M / 2);
    unsigned short* Cy1 = (unsigned short*)alloc((size_t)M * M / 2);
    unsigned short* Cy2 = (unsigned short*)alloc((size_t)M * M / 2);
    float* pms1 = alloc((size_t)512 * 2048 * 2);
    float* pms2 = alloc((size_t)512 * 2048 * 2);

    float* la2  = lg2;
    float* lbi2 = lg2 + 4096;
    float* lbj2 = lg2 + 6144;
    const float* hnx = hnAll;
    const float* hni = hnAll + 4096;
    const float* hnj = hnAll + 6144;
    const unsigned short* tdh  = thAll;
    const unsigned short* tsih = thAll + (size_t)4096 * 128;
    const unsigned short* tsjh = thAll + (size_t)6144 * 128;

    // ---- setup ----
    k_transposeW<<<128, 128, 0, stream>>>(W, WT);
    k_transform_all<<<1024, 128, 0, stream>>>(d, si, sj, WT, thAll, hnAll);
    k_log_all<<<32, 256, 0, stream>>>(h, hi, hj, lg2);

    // ---- cost matrices: 4 exact-grid dispatches ----
    CostPair cp0 = { tdh,  tsih, hnx, hni, C1,  M };
    CostPair cp1 = { tdh,  tsjh, hnx, hnj, C2,  M };
    CostPair cp2 = { tsih, tsih, hni, hni, Cy1, M };
    CostPair cp3 = { tsjh, tsjh, hnj, hnj, Cy2, M };
    k_cost_mfma<<<dim3(M / 128, N / 64), 256, 0, stream>>>(cp0);
    k_cost_mfma<<<dim3(M / 128, N / 64), 256, 0, stream>>>(cp1);
    k_cost_mfma<<<dim3(M / 128, M / 64), 256, 0, stream>>>(cp2);
    k_cost_mfma<<<dim3(M / 128, M / 64), 256, 0, stream>>>(cp3);

    // ---- eps schedule ----
    double epsl[16]; int ne = 0;
    for (double sg = 32.0; sg > 0.05; sg *= 0.5) epsl[ne++] = sg * sg;
    epsl[ne++] = 0.05 * 0.05;   // ne == 11

    for (int r = 0; r <= ne + 1; ++r) {
        const bool init = (r == 0), fin = (r == ne + 1);
        const double eps  = init ? epsl[0] : (fin ? epsl[ne - 1] : epsl[r - 1]);
        const double epsn = (r + 1 <= ne) ? epsl[r] : epsl[ne - 1];
        const int in = init ? 0 : (r - 1) & 1;
        const int o  = r & 1;

        R5Args RA;
        RA.ie2    = (float)(LOG2E / eps);
        RA.epsln2 = (float)(eps * LN2);
        RA.ie2n   = (float)(LOG2E / epsn);
        RA.alpha  = (init || fin) ? 0.0f : 0.5f;
        RA.beta   = (init || fin) ? 1.0f : 0.5f;
        RA.yblk0  = 1024;
        RA.d[0] = { C1, init ? lbi2 : WB1[in], init ? la2 : WA1[in], f1[in], la2,
                    fin ? f1f : f1[o], WA1[o], pms1, 0 };
        RA.d[1] = { C2, init ? lbj2 : WB2[in], init ? la2 : WA2[in], f2[in], la2,
                    fin ? f2f : f2[o], WA2[o], pms2, 512 };
        RA.y[0] = { Cy1, init ? lbi2 : WY1[in], gb1[in], lbi2,
                    fin ? gb1f : gb1[o], WY1[o], 1024 };
        RA.y[1] = { Cy2, init ? lbj2 : WY2[in], gb2[in], lbj2,
                    fin ? gb2f : gb2[o], WY2[o], 1280 };
        k_round6<<<1536, 256, 0, stream>>>(RA);

        C4Args CA;
        CA.epsln2 = (float)(eps * LN2);
        CA.ie2n   = (float)(LOG2E / epsn);
        CA.alpha  = RA.alpha;
        CA.beta   = RA.beta;
        CA.a[0] = { pms1, g1[in], lbi2, fin ? g1f : g1[o], WB1[o] };
        CA.a[1] = { pms2, g2[in], lbj2, fin ? g2f : g2[o], WB2[o] };
        k_comb5<<<512, 256, 0, stream>>>(CA);
    }

    k_final<<<1, 1024, 0, stream>>>(h, hi, hj, f1f, f2f, g1f, gb1f, g2f, gb2f, N, M, out);
}

// Round 12
// 295.154 us; speedup vs baseline: 1.2337x; 1.2337x over previous
//
#include <hip/hip_runtime.h>
#include <math.h>

// ---------------------------------------------------------------------------
// LinSinkhornPRModel: sigmoid(dist2 - dist1) of two Sinkhorn divergences.
//   - f_aa self-term cancels in dist2-dist1 -> C_xx never built.
//   - R11: dual row+col pass neutral at 364us (2-exp2 col path + partial
//     machinery + 2 launches/round = structural floor ~23us/round).
//   - R12: fp16 CT1/CT2 materialized by the cost kernel (LDS-transpose
//     epilogue; Cy symmetric -> reuse). Every update is a uniform row-only
//     softmin (1 exp2/elem); partials+comb deleted; 1 launch/round.
// ---------------------------------------------------------------------------

typedef __attribute__((ext_vector_type(8))) short short8;
typedef __attribute__((ext_vector_type(4))) float f32x4;
typedef __attribute__((ext_vector_type(8))) unsigned short u16x8;
typedef __attribute__((ext_vector_type(4))) unsigned short u16x4;

#define LOG2E 1.4426950408889634
#define LN2   0.6931471805599453

__device__ __forceinline__ float exp2fast(float x){
#if __has_builtin(__builtin_amdgcn_exp2f)
    return __builtin_amdgcn_exp2f(x);
#else
    return exp2f(x);
#endif
}
__device__ __forceinline__ void lse2_merge(float& m, float& s, float mo, float so){
    float M2 = fmaxf(m, mo);
    s = s * exp2fast(m - M2) + so * exp2fast(mo - M2);
    m = M2;
}
__device__ __forceinline__ unsigned short f2bf(float x){
    unsigned u = __float_as_uint(x);
    unsigned r = u + 0x7fffu + ((u >> 16) & 1u);
    return (unsigned short)(r >> 16);
}
__device__ __forceinline__ float h2f(unsigned short u){
    _Float16 h; __builtin_memcpy(&h, &u, 2); return (float)h;
}
__device__ __forceinline__ unsigned short f2h(float f){
    _Float16 h = (_Float16)f; unsigned short u; __builtin_memcpy(&u, &h, 2); return u;
}
__device__ __forceinline__ float max8(const float* v){
    return fmaxf(fmaxf(fmaxf(v[0], v[1]), fmaxf(v[2], v[3])),
                 fmaxf(fmaxf(v[4], v[5]), fmaxf(v[6], v[7])));
}

// ----------------------------- setup kernels -------------------------------

__global__ void k_transposeW(const float* __restrict__ W, float* __restrict__ WT){
    int b = blockIdx.x, t = threadIdx.x;   // WT[k][o] = W[o][k]
    WT[b * 128 + t] = W[t * 128 + b];
}

__global__ __launch_bounds__(128)
void k_transform_all(const float* __restrict__ d, const float* __restrict__ si,
                     const float* __restrict__ sj, const float* __restrict__ WT,
                     unsigned short* __restrict__ th, float* __restrict__ hn)
{
    __shared__ float xs[8][128];
    __shared__ float red[16];
    const int t = threadIdx.x;
    const int r0 = blockIdx.x * 8;
    const float* src; int sr;
    if (r0 < 4096)      { src = d;  sr = r0; }
    else if (r0 < 6144) { src = si; sr = r0 - 4096; }
    else                { src = sj; sr = r0 - 6144; }
    for (int rr = 0; rr < 8; ++rr)
        xs[rr][t] = src[(size_t)(sr + rr) * 128 + t];
    __syncthreads();
    float acc[8];
#pragma unroll
    for (int rr = 0; rr < 8; ++rr) acc[rr] = 0.f;
    for (int k = 0; k < 128; ++k) {
        float wv = WT[k * 128 + t];
#pragma unroll
        for (int rr = 0; rr < 8; ++rr) acc[rr] = fmaf(xs[rr][k], wv, acc[rr]);
    }
#pragma unroll
    for (int rr = 0; rr < 8; ++rr) {
        float a = acc[rr];
        th[(size_t)(r0 + rr) * 128 + t] = f2bf(a);
        float sq = a * a;
#pragma unroll
        for (int o = 1; o < 64; o <<= 1) sq += __shfl_xor(sq, o);
        if ((t & 63) == 0) red[(t >> 6) * 8 + rr] = sq;
    }
    __syncthreads();
    if (t < 8) hn[r0 + t] = 0.5f * (red[t] + red[8 + t]);
}

__global__ void k_log_all(const float* __restrict__ h, const float* __restrict__ hi,
                          const float* __restrict__ hj, float* __restrict__ lg)
{
    int i = blockIdx.x * 256 + threadIdx.x;   // 8192 total
    float x;
    if (i < 4096)      x = h[i];
    else if (i < 6144) x = hi[i - 4096];
    else               x = hj[i - 6144];
    lg[i] = __log2f(x);
}

// ------------------------------ cost GEMM (MFMA) ---------------------------
// C[i][j] = max(hna[i]+hnb[j]-dot, 0) fp16, single bf16 pass; optionally
// also writes CT[j][i] from the staged LDS tile (transpose epilogue).
struct CostPair {
    const unsigned short *Ah, *Bh;
    const float *hna, *hnb;
    unsigned short* C; unsigned short* CT;   // CT may be null
    int ldc; int ldct;
};

#define CPAD 136

__global__ __launch_bounds__(256)
void k_cost_mfma(CostPair P)
{
    const int i0 = blockIdx.y * 64, j0 = blockIdx.x * 128;
    const int w = threadIdx.x >> 6, lane = threadIdx.x & 63;
    const int rh = w >> 1, ch = w & 1;
    const int ar = i0 + rh * 32;
    const int bc = j0 + ch * 64;
    const int lrow = lane & 15;
    const int kgrp = (lane >> 4) * 8;

    __shared__ unsigned short lds_c[64][CPAD];

    f32x4 acc[2][4];
#pragma unroll
    for (int a = 0; a < 2; ++a)
#pragma unroll
        for (int c = 0; c < 4; ++c) acc[a][c] = (f32x4){0.f, 0.f, 0.f, 0.f};

    short8 ah[2][4], bh[4][4];
#pragma unroll
    for (int kc = 0; kc < 4; ++kc) {
#pragma unroll
        for (int f = 0; f < 2; ++f)
            ah[f][kc] = *reinterpret_cast<const short8*>(
                P.Ah + (size_t)(ar + f * 16 + lrow) * 128 + kc * 32 + kgrp);
#pragma unroll
        for (int f = 0; f < 4; ++f)
            bh[f][kc] = *reinterpret_cast<const short8*>(
                P.Bh + (size_t)(bc + f * 16 + lrow) * 128 + kc * 32 + kgrp);
    }
#pragma unroll
    for (int kc = 0; kc < 4; ++kc)
#pragma unroll
        for (int fi = 0; fi < 2; ++fi)
#pragma unroll
            for (int fj = 0; fj < 4; ++fj)
                acc[fi][fj] = __builtin_amdgcn_mfma_f32_16x16x32_bf16(
                    bh[fj][kc], ah[fi][kc], acc[fi][fj], 0, 0, 0);

    // C^T frag -> LDS stage (C-row = lane&15, C-col = (lane>>4)*4 + e)
    const int rloc = lane & 15, cloc = (lane >> 4) * 4;
#pragma unroll
    for (int fi = 0; fi < 2; ++fi) {
        int lr = rh * 32 + fi * 16 + rloc;
        float ha = P.hna[i0 + lr];
#pragma unroll
        for (int fj = 0; fj < 4; ++fj) {
            int lc = ch * 64 + fj * 16 + cloc;
            f32x4 hb = *reinterpret_cast<const f32x4*>(P.hnb + j0 + lc);
            u16x4 v;
#pragma unroll
            for (int e = 0; e < 4; ++e)
                v[e] = f2h(fmaxf(ha + hb[e] - acc[fi][fj][e], 0.f));
            *reinterpret_cast<u16x4*>(&lds_c[lr][lc]) = v;
        }
    }
    __syncthreads();
    // C store: thread t -> row t>>2, 32-col quarter t&3 (row-contiguous)
    {
        const int row = threadIdx.x >> 2, q = threadIdx.x & 3;
        const unsigned short* srcp = &lds_c[row][q * 32];
        unsigned short* dstp = P.C + (size_t)(i0 + row) * P.ldc + j0 + q * 32;
#pragma unroll
        for (int k = 0; k < 4; ++k)
            *reinterpret_cast<u16x8*>(dstp + 8 * k) =
                *reinterpret_cast<const u16x8*>(srcp + 8 * k);
    }
    // CT store: thread t -> CT row (orig col) t>>1, 32-row half t&1
    if (P.CT) {
        const int tr = threadIdx.x >> 1, half = threadIdx.x & 1;
        unsigned short* dstp = P.CT + (size_t)(j0 + tr) * P.ldct + i0 + half * 32;
#pragma unroll
        for (int k = 0; k < 4; ++k) {
            u16x8 v;
#pragma unroll
            for (int e = 0; e < 8; ++e)
                v[e] = lds_c[half * 32 + k * 8 + e][tr];
            *reinterpret_cast<u16x8*>(dstp + 8 * k) = v;
        }
    }
}

// ------------------------------ round kernel -------------------------------
// Uniform row-only softmin: 8 rows/block, thread t owns W/256 contiguous
// cols. Per row: v = Win[j] - C[row][j]*ie2, two-pass LSE (1 exp2/elem);
// 256-partial LDS reduce (stride-256, 2-way bank alias only); finalize
// vnew = alpha*fold + beta*(-eps*ln2*lse) and next-round weight wout.

struct RT7 {
    const unsigned short* C;      // [rows][W] fp16
    const float* Win;             // W-wide weights
    const float* fold; const float* logself;
    float* vout; float* wout;
    int blk0; int wide;           // wide: 0 -> W=2048, 1 -> W=4096
};
struct R7Args {
    RT7 t[6];
    float ie2, epsln2, ie2n, alpha, beta;
};

__global__ __launch_bounds__(256, 8)
void k_round7(R7Args A)
{
    __shared__ float lmS[8][256];
    __shared__ float lsS[8][256];
    const int b = blockIdx.x;
    const int tid = threadIdx.x;
    const float nie2 = -A.ie2;

    int ti = 5;
    if      (b < A.t[1].blk0) ti = 0;
    else if (b < A.t[2].blk0) ti = 1;
    else if (b < A.t[3].blk0) ti = 2;
    else if (b < A.t[4].blk0) ti = 3;
    else if (b < A.t[5].blk0) ti = 4;
    RT7 T = A.t[ti];
    const int row0 = (b - T.blk0) * 8;

    if (!T.wide) {
        const int c0 = tid * 8;
        float wb[8];
#pragma unroll
        for (int e = 0; e < 8; ++e) wb[e] = T.Win[c0 + e];
#pragma unroll
        for (int r = 0; r < 8; ++r) {
            u16x8 c = *reinterpret_cast<const u16x8*>(T.C + (size_t)(row0 + r) * 2048 + c0);
            float v[8];
#pragma unroll
            for (int e = 0; e < 8; ++e) v[e] = fmaf(h2f(c[e]), nie2, wb[e]);
            float M8 = max8(v);
            float s8 = 0.f;
#pragma unroll
            for (int e = 0; e < 8; ++e) s8 += exp2fast(v[e] - M8);
            lmS[r][tid] = M8; lsS[r][tid] = s8;
        }
    } else {
        const int c0 = tid * 16;
        float wb[16];
#pragma unroll
        for (int e = 0; e < 16; ++e) wb[e] = T.Win[c0 + e];
#pragma unroll
        for (int r = 0; r < 8; ++r) {
            const unsigned short* Cr = T.C + (size_t)(row0 + r) * 4096 + c0;
            u16x8 ca = *reinterpret_cast<const u16x8*>(Cr);
            u16x8 cb = *reinterpret_cast<const u16x8*>(Cr + 8);
            float v[16];
#pragma unroll
            for (int e = 0; e < 8; ++e) {
                v[e]     = fmaf(h2f(ca[e]), nie2, wb[e]);
                v[8 + e] = fmaf(h2f(cb[e]), nie2, wb[8 + e]);
            }
            float M = fmaxf(max8(v), max8(v + 8));
            float s = 0.f;
#pragma unroll
            for (int e = 0; e < 16; ++e) s += exp2fast(v[e] - M);
            lmS[r][tid] = M; lsS[r][tid] = s;
        }
    }
    __syncthreads();
    {
        const int row = tid >> 5, g = tid & 31;
        float m = lmS[row][g], s = lsS[row][g];
#pragma unroll
        for (int k = 1; k < 8; ++k)
            lse2_merge(m, s, lmS[row][g + 32 * k], lsS[row][g + 32 * k]);
#pragma unroll
        for (int o = 1; o < 32; o <<= 1) {
            float mo = __shfl_xor(m, o), so = __shfl_xor(s, o);
            lse2_merge(m, s, mo, so);
        }
        if (g == 0) {
            int rr = row0 + row;
            float val  = -A.epsln2 * (m + __log2f(s));
            float vnew = A.alpha * T.fold[rr] + A.beta * val;
            T.vout[rr] = vnew;
            T.wout[rr] = fmaf(vnew, A.ie2n, T.logself[rr]);
        }
    }
}

// ------------------------------ final reduce -------------------------------
__global__ __launch_bounds__(1024)
void k_final(const float* __restrict__ h, const float* __restrict__ hi,
             const float* __restrict__ hj,
             const float* __restrict__ f1f, const float* __restrict__ f2f,
             const float* __restrict__ g1f, const float* __restrict__ gb1f,
             const float* __restrict__ g2f, const float* __restrict__ gb2f,
             int N, int M, float* __restrict__ out)
{
    float acc = 0.f;
    for (int i = threadIdx.x; i < N; i += 1024)
        acc += h[i] * (f2f[i] - f1f[i]);
    for (int j = threadIdx.x; j < M; j += 1024)
        acc += hj[j] * (g2f[j] - gb2f[j]) - hi[j] * (g1f[j] - gb1f[j]);
#pragma unroll
    for (int o = 32; o; o >>= 1) acc += __shfl_xor(acc, o);
    __shared__ float red[16];
    const int lane = threadIdx.x & 63, w = threadIdx.x >> 6;
    if (lane == 0) red[w] = acc;
    __syncthreads();
    if (threadIdx.x == 0) {
        float t = 0.f;
        for (int q = 0; q < 16; ++q) t += red[q];
        out[0] = 1.f / (1.f + expf(-t));   // SCALING_FACTOR = 1
    }
}

// ------------------------------ orchestration ------------------------------

extern "C" void kernel_launch(void* const* d_in, const int* in_sizes, int n_in,
                              void* d_out, int out_size, void* d_ws, size_t ws_size,
                              hipStream_t stream)
{
    const float* d  = (const float*)d_in[0];
    const float* si = (const float*)d_in[1];
    const float* sj = (const float*)d_in[2];
    const float* h  = (const float*)d_in[3];
    const float* hi = (const float*)d_in[4];
    const float* hj = (const float*)d_in[5];
    const float* W  = (const float*)d_in[6];
    float* out = (float*)d_out;

    const int N = 4096, M = 2048;
    (void)in_sizes; (void)n_in; (void)out_size; (void)ws_size;

    float* ws = (float*)d_ws;
    size_t off = 0;
    auto alloc = [&](size_t n) { float* p = ws + off; off += (n + 63) & ~(size_t)63; return p; };

    float* WT    = alloc(128 * 128);
    float* lg2   = alloc(8192);
    float* hnAll = alloc(8192);
    unsigned short* thAll = (unsigned short*)alloc(8192 * 128 / 2);
    float* f1[2]  = { alloc(N), alloc(N) };
    float* f2[2]  = { alloc(N), alloc(N) };
    float* g1[2]  = { alloc(M), alloc(M) };
    float* g2[2]  = { alloc(M), alloc(M) };
    float* gb1[2] = { alloc(M), alloc(M) };
    float* gb2[2] = { alloc(M), alloc(M) };
    float* WA1[2] = { alloc(N), alloc(N) };
    float* WA2[2] = { alloc(N), alloc(N) };
    float* WB1[2] = { alloc(M), alloc(M) };
    float* WB2[2] = { alloc(M), alloc(M) };
    float* WY1[2] = { alloc(M), alloc(M) };
    float* WY2[2] = { alloc(M), alloc(M) };
    float* f1f = alloc(N); float* f2f = alloc(N);
    float* g1f = alloc(M); float* g2f = alloc(M);
    float* gb1f = alloc(M); float* gb2f = alloc(M);
    unsigned short* C1  = (unsigned short*)alloc((size_t)N * M / 2);
    unsigned short* C2  = (unsigned short*)alloc((size_t)N * M / 2);
    unsigned short* CT1 = (unsigned short*)alloc((size_t)M * N / 2);
    unsigned short* CT2 = (unsigned short*)alloc((size_t)M * N / 2);
    unsigned short* Cy1 = (unsigned short*)alloc((size_t)M * M / 2);
    unsigned short* Cy2 = (unsigned short*)alloc((size_t)M * M / 2);

    float* la2  = lg2;
    float* lbi2 = lg2 + 4096;
    float* lbj2 = lg2 + 6144;
    const float* hnx = hnAll;
    const float* hni = hnAll + 4096;
    const float* hnj = hnAll + 6144;
    const unsigned short* tdh  = thAll;
    const unsigned short* tsih = thAll + (size_t)4096 * 128;
    const unsigned short* tsjh = thAll + (size_t)6144 * 128;

    // ---- setup ----
    k_transposeW<<<128, 128, 0, stream>>>(W, WT);
    k_transform_all<<<1024, 128, 0, stream>>>(d, si, sj, WT, thAll, hnAll);
    k_log_all<<<32, 256, 0, stream>>>(h, hi, hj, lg2);

    // ---- cost matrices (+ CT for xy) ----
    CostPair cp0 = { tdh,  tsih, hnx, hni, C1,  CT1,     M, N };
    CostPair cp1 = { tdh,  tsjh, hnx, hnj, C2,  CT2,     M, N };
    CostPair cp2 = { tsih, tsih, hni, hni, Cy1, nullptr, M, 0 };
    CostPair cp3 = { tsjh, tsjh, hnj, hnj, Cy2, nullptr, M, 0 };
    k_cost_mfma<<<dim3(M / 128, N / 64), 256, 0, stream>>>(cp0);
    k_cost_mfma<<<dim3(M / 128, N / 64), 256, 0, stream>>>(cp1);
    k_cost_mfma<<<dim3(M / 128, M / 64), 256, 0, stream>>>(cp2);
    k_cost_mfma<<<dim3(M / 128, M / 64), 256, 0, stream>>>(cp3);

    // ---- eps schedule ----
    double epsl[16]; int ne = 0;
    for (double sg = 32.0; sg > 0.05; sg *= 0.5) epsl[ne++] = sg * sg;
    epsl[ne++] = 0.05 * 0.05;   // ne == 11

    for (int r = 0; r <= ne + 1; ++r) {
        const bool init = (r == 0), fin = (r == ne + 1);
        const double eps  = init ? epsl[0] : (fin ? epsl[ne - 1] : epsl[r - 1]);
        const double epsn = (r + 1 <= ne) ? epsl[r] : epsl[ne - 1];
        const int in = init ? 0 : (r - 1) & 1;
        const int o  = r & 1;

        R7Args A;
        A.ie2    = (float)(LOG2E / eps);
        A.epsln2 = (float)(eps * LN2);
        A.ie2n   = (float)(LOG2E / epsn);
        A.alpha  = (init || fin) ? 0.0f : 0.5f;
        A.beta   = (init || fin) ? 1.0f : 0.5f;
        // f updates over C (narrow), g updates over CT (wide), gb over Cy
        A.t[0] = { C1,  init ? lbi2 : WB1[in], f1[in],  la2,
                   fin ? f1f  : f1[o],  WA1[o],    0, 0 };
        A.t[1] = { C2,  init ? lbj2 : WB2[in], f2[in],  la2,
                   fin ? f2f  : f2[o],  WA2[o],  512, 0 };
        A.t[2] = { CT1, init ? la2  : WA1[in], g1[in],  lbi2,
                   fin ? g1f  : g1[o],  WB1[o], 1024, 1 };
        A.t[3] = { CT2, init ? la2  : WA2[in], g2[in],  lbj2,
                   fin ? g2f  : g2[o],  WB2[o], 1280, 1 };
        A.t[4] = { Cy1, init ? lbi2 : WY1[in], gb1[in], lbi2,
                   fin ? gb1f : gb1[o], WY1[o], 1536, 0 };
        A.t[5] = { Cy2, init ? lbj2 : WY2[in], gb2[in], lbj2,
                   fin ? gb2f : gb2[o], WY2[o], 1792, 0 };
        k_round7<<<2048, 256, 0, stream>>>(A);
    }

    k_final<<<1, 1024, 0, stream>>>(h, hi, hj, f1f, f2f, g1f, gb1f, g2f, gb2f, N, M, out);
}

// Round 13
// 272.138 us; speedup vs baseline: 1.3380x; 1.0846x over previous
//
#include <hip/hip_runtime.h>
#include <math.h>

// ---------------------------------------------------------------------------
// LinSinkhornPRModel: sigmoid(dist2 - dist1) of two Sinkhorn divergences.
//   - f_aa self-term cancels in dist2-dist1 -> C_xx never built.
//   - R12: fp16 CT materialized by cost kernel; uniform row-only rounds,
//     1 launch/round (295us).
//   - R13: all 4 cost GEMMs in ONE launch (linear block ranges, 2560 blocks,
//     no idle blocks -- cp2/cp3 were 1 block/CU serial); transposeW+log
//     merged into one setup kernel.
// ---------------------------------------------------------------------------

typedef __attribute__((ext_vector_type(8))) short short8;
typedef __attribute__((ext_vector_type(4))) float f32x4;
typedef __attribute__((ext_vector_type(8))) unsigned short u16x8;
typedef __attribute__((ext_vector_type(4))) unsigned short u16x4;

#define LOG2E 1.4426950408889634
#define LN2   0.6931471805599453

__device__ __forceinline__ float exp2fast(float x){
#if __has_builtin(__builtin_amdgcn_exp2f)
    return __builtin_amdgcn_exp2f(x);
#else
    return exp2f(x);
#endif
}
__device__ __forceinline__ void lse2_merge(float& m, float& s, float mo, float so){
    float M2 = fmaxf(m, mo);
    s = s * exp2fast(m - M2) + so * exp2fast(mo - M2);
    m = M2;
}
__device__ __forceinline__ unsigned short f2bf(float x){
    unsigned u = __float_as_uint(x);
    unsigned r = u + 0x7fffu + ((u >> 16) & 1u);
    return (unsigned short)(r >> 16);
}
__device__ __forceinline__ float h2f(unsigned short u){
    _Float16 h; __builtin_memcpy(&h, &u, 2); return (float)h;
}
__device__ __forceinline__ unsigned short f2h(float f){
    _Float16 h = (_Float16)f; unsigned short u; __builtin_memcpy(&u, &h, 2); return u;
}
__device__ __forceinline__ float max8(const float* v){
    return fmaxf(fmaxf(fmaxf(v[0], v[1]), fmaxf(v[2], v[3])),
                 fmaxf(fmaxf(v[4], v[5]), fmaxf(v[6], v[7])));
}

// ----------------------------- setup kernels -------------------------------

// blocks 0-127: WT[k][o] = W[o][k];  blocks 128-159: lg = log2(prob vectors)
__global__ __launch_bounds__(256)
void k_setup(const float* __restrict__ W, float* __restrict__ WT,
             const float* __restrict__ h, const float* __restrict__ hi,
             const float* __restrict__ hj, float* __restrict__ lg)
{
    const int b = blockIdx.x, t = threadIdx.x;
    if (b < 64) {
        int bb = b * 2 + (t >> 7), tt = t & 127;
        WT[bb * 128 + tt] = W[tt * 128 + bb];
        return;
    }
    int i = (b - 64) * 256 + t;   // 8192 total
    float x;
    if (i < 4096)      x = h[i];
    else if (i < 6144) x = hi[i - 4096];
    else               x = hj[i - 6144];
    lg[i] = __log2f(x);
}

__global__ __launch_bounds__(128)
void k_transform_all(const float* __restrict__ d, const float* __restrict__ si,
                     const float* __restrict__ sj, const float* __restrict__ WT,
                     unsigned short* __restrict__ th, float* __restrict__ hn)
{
    __shared__ float xs[8][128];
    __shared__ float red[16];
    const int t = threadIdx.x;
    const int r0 = blockIdx.x * 8;
    const float* src; int sr;
    if (r0 < 4096)      { src = d;  sr = r0; }
    else if (r0 < 6144) { src = si; sr = r0 - 4096; }
    else                { src = sj; sr = r0 - 6144; }
    for (int rr = 0; rr < 8; ++rr)
        xs[rr][t] = src[(size_t)(sr + rr) * 128 + t];
    __syncthreads();
    float acc[8];
#pragma unroll
    for (int rr = 0; rr < 8; ++rr) acc[rr] = 0.f;
    for (int k = 0; k < 128; ++k) {
        float wv = WT[k * 128 + t];
#pragma unroll
        for (int rr = 0; rr < 8; ++rr) acc[rr] = fmaf(xs[rr][k], wv, acc[rr]);
    }
#pragma unroll
    for (int rr = 0; rr < 8; ++rr) {
        float a = acc[rr];
        th[(size_t)(r0 + rr) * 128 + t] = f2bf(a);
        float sq = a * a;
#pragma unroll
        for (int o = 1; o < 64; o <<= 1) sq += __shfl_xor(sq, o);
        if ((t & 63) == 0) red[(t >> 6) * 8 + rr] = sq;
    }
    __syncthreads();
    if (t < 8) hn[r0 + t] = 0.5f * (red[t] + red[8 + t]);
}

// ------------------------------ cost GEMM (MFMA) ---------------------------
// C[i][j] = max(hna[i]+hnb[j]-dot, 0) fp16, single bf16 pass; optionally
// also writes CT[j][i]. All 4 matrices in one launch, linear block ranges.
struct CostPair {
    const unsigned short *Ah, *Bh;
    const float *hna, *hnb;
    unsigned short* C; unsigned short* CT;   // CT may be null
    int ldc; int ldct;
    int blk0; int nbx;                        // linear range start, x-blocks
};
struct CostQuad { CostPair p[4]; };

#define CPAD 136

__global__ __launch_bounds__(256)
void k_cost_mfma(CostQuad Q)
{
    const int b = blockIdx.x;
    CostPair P = Q.p[3];
    if      (b < Q.p[1].blk0) P = Q.p[0];
    else if (b < Q.p[2].blk0) P = Q.p[1];
    else if (b < Q.p[3].blk0) P = Q.p[2];
    const int bl = b - P.blk0;
    const int i0 = (bl / P.nbx) * 64, j0 = (bl % P.nbx) * 128;
    const int w = threadIdx.x >> 6, lane = threadIdx.x & 63;
    const int rh = w >> 1, ch = w & 1;
    const int ar = i0 + rh * 32;
    const int bc = j0 + ch * 64;
    const int lrow = lane & 15;
    const int kgrp = (lane >> 4) * 8;

    __shared__ unsigned short lds_c[64][CPAD];

    f32x4 acc[2][4];
#pragma unroll
    for (int a = 0; a < 2; ++a)
#pragma unroll
        for (int c = 0; c < 4; ++c) acc[a][c] = (f32x4){0.f, 0.f, 0.f, 0.f};

    short8 ah[2][4], bh[4][4];
#pragma unroll
    for (int kc = 0; kc < 4; ++kc) {
#pragma unroll
        for (int f = 0; f < 2; ++f)
            ah[f][kc] = *reinterpret_cast<const short8*>(
                P.Ah + (size_t)(ar + f * 16 + lrow) * 128 + kc * 32 + kgrp);
#pragma unroll
        for (int f = 0; f < 4; ++f)
            bh[f][kc] = *reinterpret_cast<const short8*>(
                P.Bh + (size_t)(bc + f * 16 + lrow) * 128 + kc * 32 + kgrp);
    }
#pragma unroll
    for (int kc = 0; kc < 4; ++kc)
#pragma unroll
        for (int fi = 0; fi < 2; ++fi)
#pragma unroll
            for (int fj = 0; fj < 4; ++fj)
                acc[fi][fj] = __builtin_amdgcn_mfma_f32_16x16x32_bf16(
                    bh[fj][kc], ah[fi][kc], acc[fi][fj], 0, 0, 0);

    // C^T frag -> LDS stage (C-row = lane&15, C-col = (lane>>4)*4 + e)
    const int rloc = lane & 15, cloc = (lane >> 4) * 4;
#pragma unroll
    for (int fi = 0; fi < 2; ++fi) {
        int lr = rh * 32 + fi * 16 + rloc;
        float ha = P.hna[i0 + lr];
#pragma unroll
        for (int fj = 0; fj < 4; ++fj) {
            int lc = ch * 64 + fj * 16 + cloc;
            f32x4 hb = *reinterpret_cast<const f32x4*>(P.hnb + j0 + lc);
            u16x4 v;
#pragma unroll
            for (int e = 0; e < 4; ++e)
                v[e] = f2h(fmaxf(ha + hb[e] - acc[fi][fj][e], 0.f));
            *reinterpret_cast<u16x4*>(&lds_c[lr][lc]) = v;
        }
    }
    __syncthreads();
    // C store: thread t -> row t>>2, 32-col quarter t&3 (row-contiguous)
    {
        const int row = threadIdx.x >> 2, q = threadIdx.x & 3;
        const unsigned short* srcp = &lds_c[row][q * 32];
        unsigned short* dstp = P.C + (size_t)(i0 + row) * P.ldc + j0 + q * 32;
#pragma unroll
        for (int k = 0; k < 4; ++k)
            *reinterpret_cast<u16x8*>(dstp + 8 * k) =
                *reinterpret_cast<const u16x8*>(srcp + 8 * k);
    }
    // CT store: thread t -> CT row (orig col) t>>1, 32-row half t&1
    if (P.CT) {
        const int tr = threadIdx.x >> 1, half = threadIdx.x & 1;
        unsigned short* dstp = P.CT + (size_t)(j0 + tr) * P.ldct + i0 + half * 32;
#pragma unroll
        for (int k = 0; k < 4; ++k) {
            u16x8 v;
#pragma unroll
            for (int e = 0; e < 8; ++e)
                v[e] = lds_c[half * 32 + k * 8 + e][tr];
            *reinterpret_cast<u16x8*>(dstp + 8 * k) = v;
        }
    }
}

// ------------------------------ round kernel -------------------------------
// Uniform row-only softmin: 8 rows/block, thread t owns W/256 contiguous
// cols. Per row: v = Win[j] - C[row][j]*ie2, two-pass LSE (1 exp2/elem);
// 256-partial LDS reduce; finalize vnew + next-round weight wout.

struct RT7 {
    const unsigned short* C;      // [rows][W] fp16
    const float* Win;             // W-wide weights
    const float* fold; const float* logself;
    float* vout; float* wout;
    int blk0; int wide;           // wide: 0 -> W=2048, 1 -> W=4096
};
struct R7Args {
    RT7 t[6];
    float ie2, epsln2, ie2n, alpha, beta;
};

__global__ __launch_bounds__(256, 8)
void k_round7(R7Args A)
{
    __shared__ float lmS[8][256];
    __shared__ float lsS[8][256];
    const int b = blockIdx.x;
    const int tid = threadIdx.x;
    const float nie2 = -A.ie2;

    int ti = 5;
    if      (b < A.t[1].blk0) ti = 0;
    else if (b < A.t[2].blk0) ti = 1;
    else if (b < A.t[3].blk0) ti = 2;
    else if (b < A.t[4].blk0) ti = 3;
    else if (b < A.t[5].blk0) ti = 4;
    RT7 T = A.t[ti];
    const int row0 = (b - T.blk0) * 8;

    if (!T.wide) {
        const int c0 = tid * 8;
        float wb[8];
#pragma unroll
        for (int e = 0; e < 8; ++e) wb[e] = T.Win[c0 + e];
#pragma unroll
        for (int r = 0; r < 8; ++r) {
            u16x8 c = *reinterpret_cast<const u16x8*>(T.C + (size_t)(row0 + r) * 2048 + c0);
            float v[8];
#pragma unroll
            for (int e = 0; e < 8; ++e) v[e] = fmaf(h2f(c[e]), nie2, wb[e]);
            float M8 = max8(v);
            float s8 = 0.f;
#pragma unroll
            for (int e = 0; e < 8; ++e) s8 += exp2fast(v[e] - M8);
            lmS[r][tid] = M8; lsS[r][tid] = s8;
        }
    } else {
        const int c0 = tid * 16;
        float wb[16];
#pragma unroll
        for (int e = 0; e < 16; ++e) wb[e] = T.Win[c0 + e];
#pragma unroll
        for (int r = 0; r < 8; ++r) {
            const unsigned short* Cr = T.C + (size_t)(row0 + r) * 4096 + c0;
            u16x8 ca = *reinterpret_cast<const u16x8*>(Cr);
            u16x8 cb = *reinterpret_cast<const u16x8*>(Cr + 8);
            float v[16];
#pragma unroll
            for (int e = 0; e < 8; ++e) {
                v[e]     = fmaf(h2f(ca[e]), nie2, wb[e]);
                v[8 + e] = fmaf(h2f(cb[e]), nie2, wb[8 + e]);
            }
            float M = fmaxf(max8(v), max8(v + 8));
            float s = 0.f;
#pragma unroll
            for (int e = 0; e < 16; ++e) s += exp2fast(v[e] - M);
            lmS[r][tid] = M; lsS[r][tid] = s;
        }
    }
    __syncthreads();
    {
        const int row = tid >> 5, g = tid & 31;
        float m = lmS[row][g], s = lsS[row][g];
#pragma unroll
        for (int k = 1; k < 8; ++k)
            lse2_merge(m, s, lmS[row][g + 32 * k], lsS[row][g + 32 * k]);
#pragma unroll
        for (int o = 1; o < 32; o <<= 1) {
            float mo = __shfl_xor(m, o), so = __shfl_xor(s, o);
            lse2_merge(m, s, mo, so);
        }
        if (g == 0) {
            int rr = row0 + row;
            float val  = -A.epsln2 * (m + __log2f(s));
            float vnew = A.alpha * T.fold[rr] + A.beta * val;
            T.vout[rr] = vnew;
            T.wout[rr] = fmaf(vnew, A.ie2n, T.logself[rr]);
        }
    }
}

// ------------------------------ final reduce -------------------------------
__global__ __launch_bounds__(1024)
void k_final(const float* __restrict__ h, const float* __restrict__ hi,
             const float* __restrict__ hj,
             const float* __restrict__ f1f, const float* __restrict__ f2f,
             const float* __restrict__ g1f, const float* __restrict__ gb1f,
             const float* __restrict__ g2f, const float* __restrict__ gb2f,
             int N, int M, float* __restrict__ out)
{
    float acc = 0.f;
    for (int i = threadIdx.x; i < N; i += 1024)
        acc += h[i] * (f2f[i] - f1f[i]);
    for (int j = threadIdx.x; j < M; j += 1024)
        acc += hj[j] * (g2f[j] - gb2f[j]) - hi[j] * (g1f[j] - gb1f[j]);
#pragma unroll
    for (int o = 32; o; o >>= 1) acc += __shfl_xor(acc, o);
    __shared__ float red[16];
    const int lane = threadIdx.x & 63, w = threadIdx.x >> 6;
    if (lane == 0) red[w] = acc;
    __syncthreads();
    if (threadIdx.x == 0) {
        float t = 0.f;
        for (int q = 0; q < 16; ++q) t += red[q];
        out[0] = 1.f / (1.f + expf(-t));   // SCALING_FACTOR = 1
    }
}

// ------------------------------ orchestration ------------------------------

extern "C" void kernel_launch(void* const* d_in, const int* in_sizes, int n_in,
                              void* d_out, int out_size, void* d_ws, size_t ws_size,
                              hipStream_t stream)
{
    const float* d  = (const float*)d_in[0];
    const float* si = (const float*)d_in[1];
    const float* sj = (const float*)d_in[2];
    const float* h  = (const float*)d_in[3];
    const float* hi = (const float*)d_in[4];
    const float* hj = (const float*)d_in[5];
    const float* W  = (const float*)d_in[6];
    float* out = (float*)d_out;

    const int N = 4096, M = 2048;
    (void)in_sizes; (void)n_in; (void)out_size; (void)ws_size;

    float* ws = (float*)d_ws;
    size_t off = 0;
    auto alloc = [&](size_t n) { float* p = ws + off; off += (n + 63) & ~(size_t)63; return p; };

    float* WT    = alloc(128 * 128);
    float* lg2   = alloc(8192);
    float* hnAll = alloc(8192);
    unsigned short* thAll = (unsigned short*)alloc(8192 * 128 / 2);
    float* f1[2]  = { alloc(N), alloc(N) };
    float* f2[2]  = { alloc(N), alloc(N) };
    float* g1[2]  = { alloc(M), alloc(M) };
    float* g2[2]  = { alloc(M), alloc(M) };
    float* gb1[2] = { alloc(M), alloc(M) };
    float* gb2[2] = { alloc(M), alloc(M) };
    float* WA1[2] = { alloc(N), alloc(N) };
    float* WA2[2] = { alloc(N), alloc(N) };
    float* WB1[2] = { alloc(M), alloc(M) };
    float* WB2[2] = { alloc(M), alloc(M) };
    float* WY1[2] = { alloc(M), alloc(M) };
    float* WY2[2] = { alloc(M), alloc(M) };
    float* f1f = alloc(N); float* f2f = alloc(N);
    float* g1f = alloc(M); float* g2f = alloc(M);
    float* gb1f = alloc(M); float* gb2f = alloc(M);
    unsigned short* C1  = (unsigned short*)alloc((size_t)N * M / 2);
    unsigned short* C2  = (unsigned short*)alloc((size_t)N * M / 2);
    unsigned short* CT1 = (unsigned short*)alloc((size_t)M * N / 2);
    unsigned short* CT2 = (unsigned short*)alloc((size_t)M * N / 2);
    unsigned short* Cy1 = (unsigned short*)alloc((size_t)M * M / 2);
    unsigned short* Cy2 = (unsigned short*)alloc((size_t)M * M / 2);

    float* la2  = lg2;
    float* lbi2 = lg2 + 4096;
    float* lbj2 = lg2 + 6144;
    const float* hnx = hnAll;
    const float* hni = hnAll + 4096;
    const float* hnj = hnAll + 6144;
    const unsigned short* tdh  = thAll;
    const unsigned short* tsih = thAll + (size_t)4096 * 128;
    const unsigned short* tsjh = thAll + (size_t)6144 * 128;

    // ---- setup ----
    k_setup<<<96, 256, 0, stream>>>(W, WT, h, hi, hj, lg2);
    k_transform_all<<<1024, 128, 0, stream>>>(d, si, sj, WT, thAll, hnAll);

    // ---- cost matrices (+ CT for xy): ONE launch, 2560 blocks ----
    CostQuad Q;
    Q.p[0] = { tdh,  tsih, hnx, hni, C1,  CT1,     M, N,    0, 16 };
    Q.p[1] = { tdh,  tsjh, hnx, hnj, C2,  CT2,     M, N, 1024, 16 };
    Q.p[2] = { tsih, tsih, hni, hni, Cy1, nullptr, M, 0, 2048, 16 };
    Q.p[3] = { tsjh, tsjh, hnj, hnj, Cy2, nullptr, M, 0, 2304, 16 };
    k_cost_mfma<<<2560, 256, 0, stream>>>(Q);

    // ---- eps schedule ----
    double epsl[16]; int ne = 0;
    for (double sg = 32.0; sg > 0.05; sg *= 0.5) epsl[ne++] = sg * sg;
    epsl[ne++] = 0.05 * 0.05;   // ne == 11

    for (int r = 0; r <= ne + 1; ++r) {
        const bool init = (r == 0), fin = (r == ne + 1);
        const double eps  = init ? epsl[0] : (fin ? epsl[ne - 1] : epsl[r - 1]);
        const double epsn = (r + 1 <= ne) ? epsl[r] : epsl[ne - 1];
        const int in = init ? 0 : (r - 1) & 1;
        const int o  = r & 1;

        R7Args A;
        A.ie2    = (float)(LOG2E / eps);
        A.epsln2 = (float)(eps * LN2);
        A.ie2n   = (float)(LOG2E / epsn);
        A.alpha  = (init || fin) ? 0.0f : 0.5f;
        A.beta   = (init || fin) ? 1.0f : 0.5f;
        // f updates over C (narrow), g updates over CT (wide), gb over Cy
        A.t[0] = { C1,  init ? lbi2 : WB1[in], f1[in],  la2,
                   fin ? f1f  : f1[o],  WA1[o],    0, 0 };
        A.t[1] = { C2,  init ? lbj2 : WB2[in], f2[in],  la2,
                   fin ? f2f  : f2[o],  WA2[o],  512, 0 };
        A.t[2] = { CT1, init ? la2  : WA1[in], g1[in],  lbi2,
                   fin ? g1f  : g1[o],  WB1[o], 1024, 1 };
        A.t[3] = { CT2, init ? la2  : WA2[in], g2[in],  lbj2,
                   fin ? g2f  : g2[o],  WB2[o], 1280, 1 };
        A.t[4] = { Cy1, init ? lbi2 : WY1[in], gb1[in], lbi2,
                   fin ? gb1f : gb1[o], WY1[o], 1536, 0 };
        A.t[5] = { Cy2, init ? lbj2 : WY2[in], gb2[in], lbj2,
                   fin ? gb2f : gb2[o], WY2[o], 1792, 0 };
        k_round7<<<2048, 256, 0, stream>>>(A);
    }

    k_final<<<1, 1024, 0, stream>>>(h, hi, hj, f1f, f2f, g1f, gb1f, g2f, gb2f, N, M, out);
}